// Round 8
// baseline (394.222 us; speedup 1.0000x reference)
//
#include <hip/hip_runtime.h>
#include <hip/hip_bf16.h>

#define BB 8
#define FF 64
#define NPTS 100000
#define RES 32
#define R3 (RES*RES*RES)
#define EPSV 1e-6f
#define SEGS (BB*R3)            // 262144 voxel cells total
#define NPTS_TOT (BB*NPTS)      // 800000 points
#define HALF_VOX (R3/2)         // 16384 voxels per half -> 64 KB f32 LDS

static constexpr size_t GRID_ELEMS = (size_t)BB * FF * R3;   // 16,777,216

// ---------------- Kernel Z: fast zero (sums/rad/counts) ----------------
__global__ void k_zero(uint4* __restrict__ p, int n16) {
    int i = blockIdx.x * 256 + threadIdx.x;
    if (i < n16) p[i] = make_uint4(0u, 0u, 0u, 0u);
}

// ---------------- Kernel A: per-batch coordinate sums ----------------
#define NB_STAT 64
__global__ void k_sum_coords(const float* __restrict__ coords, float* __restrict__ sums) {
    int b = blockIdx.x / NB_STAT;
    int chunk = blockIdx.x % NB_STAT;
    const float* cb = coords + (size_t)b * 3 * NPTS;
    float sx = 0.f, sy = 0.f, sz = 0.f;
    for (int i = chunk * blockDim.x + threadIdx.x; i < NPTS; i += NB_STAT * blockDim.x) {
        sx += cb[i];
        sy += cb[NPTS + i];
        sz += cb[2 * NPTS + i];
    }
    for (int off = 32; off; off >>= 1) {
        sx += __shfl_down(sx, off);
        sy += __shfl_down(sy, off);
        sz += __shfl_down(sz, off);
    }
    __shared__ float lsx[4], lsy[4], lsz[4];
    int lane = threadIdx.x & 63, wid = threadIdx.x >> 6;
    if (lane == 0) { lsx[wid] = sx; lsy[wid] = sy; lsz[wid] = sz; }
    __syncthreads();
    if (threadIdx.x == 0) {
        float tx = 0.f, ty = 0.f, tz = 0.f;
        for (int w = 0; w < 4; ++w) { tx += lsx[w]; ty += lsy[w]; tz += lsz[w]; }
        atomicAdd(&sums[b * 3 + 0], tx);
        atomicAdd(&sums[b * 3 + 1], ty);
        atomicAdd(&sums[b * 3 + 2], tz);
    }
}

// ---------------- Kernel B: per-batch max radius ----------------
__global__ void k_radius(const float* __restrict__ coords, const float* __restrict__ sums,
                         int* __restrict__ rad_bits) {
    int b = blockIdx.x / NB_STAT;
    int chunk = blockIdx.x % NB_STAT;
    const float* cb = coords + (size_t)b * 3 * NPTS;
    float mx = sums[b * 3 + 0] / (float)NPTS;
    float my = sums[b * 3 + 1] / (float)NPTS;
    float mz = sums[b * 3 + 2] / (float)NPTS;
    float mval = 0.f;
    for (int i = chunk * blockDim.x + threadIdx.x; i < NPTS; i += NB_STAT * blockDim.x) {
        float x = cb[i] - mx;
        float y = cb[NPTS + i] - my;
        float z = cb[2 * NPTS + i] - mz;
        float nrm = sqrtf(x * x + y * y + z * z);
        mval = fmaxf(mval, nrm);
    }
    for (int off = 32; off; off >>= 1) mval = fmaxf(mval, __shfl_down(mval, off));
    __shared__ float lm[4];
    int lane = threadIdx.x & 63, wid = threadIdx.x >> 6;
    if (lane == 0) lm[wid] = mval;
    __syncthreads();
    if (threadIdx.x == 0) {
        float t = fmaxf(fmaxf(lm[0], lm[1]), fmaxf(lm[2], lm[3]));
        atomicMax(&rad_bits[b], __float_as_int(t));  // norms >= 0: int order == float order
    }
}

// ---------------- Kernel C: per-point voxelize + norm_coords + counts ----------------
__global__ void k_voxelize(const float* __restrict__ coords, const float* __restrict__ sums,
                           const int* __restrict__ rad_bits, float* __restrict__ norm_out,
                           int* __restrict__ voxidx, int* __restrict__ counts) {
    int tid = blockIdx.x * blockDim.x + threadIdx.x;
    if (tid >= NPTS_TOT) return;
    int b = tid / NPTS, n = tid % NPTS;
    const float* cb = coords + (size_t)b * 3 * NPTS;
    float mx = sums[b * 3 + 0] / (float)NPTS;
    float my = sums[b * 3 + 1] / (float)NPTS;
    float mz = sums[b * 3 + 2] / (float)NPTS;
    float r = __int_as_float(rad_bits[b]);
    float d = 2.0f * r + EPSV;
    float x = (cb[n] - mx) / d + 0.5f;
    float y = (cb[NPTS + n] - my) / d + 0.5f;
    float z = (cb[2 * NPTS + n] - mz) / d + 0.5f;
    float nx = fminf(fmaxf(x * (float)RES, 0.0f), (float)(RES - 1));
    float ny = fminf(fmaxf(y * (float)RES, 0.0f), (float)(RES - 1));
    float nz = fminf(fmaxf(z * (float)RES, 0.0f), (float)(RES - 1));
    float* nb_ = norm_out + (size_t)b * 3 * NPTS;
    nb_[n] = nx;
    nb_[NPTS + n] = ny;
    nb_[2 * NPTS + n] = nz;
    int vx = (int)rintf(nx), vy = (int)rintf(ny), vz = (int)rintf(nz);
    int idx = (vx * RES + vy) * RES + vz;
    voxidx[tid] = idx;
    atomicAdd(&counts[b * R3 + idx], 1);
}

// ---------------- Kernel D: direct LDS-accumulate, one block per (b, f, voxel-half) ----
// Streams features[b][f][:] (400 KB, float4) + voxidx[b][:] (L2/L3-resident re-read),
// atomicAdd into a 64 KB LDS voxel slab, then writes grid[b][f][half] coalesced with
// the count-divide fused. No sort, no scatter, f32 accumulation.
__global__ __launch_bounds__(256) void k_accum(const float* __restrict__ features,
                                               const int* __restrict__ voxidx,
                                               const int* __restrict__ counts,
                                               float* __restrict__ grid) {
    __shared__ float vox[HALF_VOX];    // 64 KB
    // XCD-aware swizzle: blocks round-robin XCDs by hardware blockIdx (xcd = bid%8).
    // Map so each XCD owns a contiguous run of (b,f) pairs and processes the two
    // halves of a pair back-to-back -> second features read hits that XCD's caches.
    int bid = blockIdx.x;              // [0, 1024)
    int xcd = bid & 7;
    int c = bid >> 3;                  // [0, 128) per XCD
    int pairid = xcd * 64 + (c >> 1);  // [0, 512) = b*64+f
    int half = c & 1;

    int bf = pairid;                   // b*FF + f
    int b = bf >> 6;
    const float4* frow = (const float4*)(features + (size_t)bf * NPTS);
    const int4* vrow = (const int4*)(voxidx + (size_t)b * NPTS);
    int vbase = half << 14;            // half * 16384

    for (int i = threadIdx.x; i < HALF_VOX; i += 256) vox[i] = 0.f;
    __syncthreads();

    const int NV = NPTS / 4;           // 25000
#pragma unroll 2
    for (int i = threadIdx.x; i < NV; i += 256) {
        float4 f4 = frow[i];
        int4 v4 = vrow[i];
        int r0 = v4.x - vbase, r1 = v4.y - vbase, r2 = v4.z - vbase, r3 = v4.w - vbase;
        if ((unsigned)r0 < HALF_VOX) atomicAdd(&vox[r0], f4.x);
        if ((unsigned)r1 < HALF_VOX) atomicAdd(&vox[r1], f4.y);
        if ((unsigned)r2 < HALF_VOX) atomicAdd(&vox[r2], f4.z);
        if ((unsigned)r3 < HALF_VOX) atomicAdd(&vox[r3], f4.w);
    }
    __syncthreads();

    const int* crow = counts + b * R3 + vbase;
    float* grow = grid + (size_t)bf * R3 + vbase;
    for (int i = threadIdx.x; i < HALF_VOX; i += 256) {
        int cnt = crow[i];
        grow[i] = (cnt > 0) ? vox[i] / (float)cnt : 0.f;   // empty voxels stay 0
    }
}

extern "C" void kernel_launch(void* const* d_in, const int* in_sizes, int n_in,
                              void* d_out, int out_size, void* d_ws, size_t ws_size,
                              hipStream_t stream) {
    const float* features = (const float*)d_in[0];
    const float* coords = (const float*)d_in[1];
    float* out = (float*)d_out;
    float* grid = out;                      // [B,F,R,R,R]
    float* norm_out = out + GRID_ELEMS;     // [B,3,N]

    char* ws = (char*)d_ws;
    size_t off_sums   = 0;                               // 24 floats
    size_t off_rad    = 128;                             // 8 ints
    size_t off_counts = 256;                             // SEGS ints (1 MB)
    size_t off_vox    = off_counts + (size_t)SEGS * 4;   // NPTS_TOT ints (3.2 MB)

    float* sums   = (float*)(ws + off_sums);
    int* rad_bits = (int*)(ws + off_rad);
    int* counts   = (int*)(ws + off_counts);
    int* voxidx   = (int*)(ws + off_vox);

    // zero sums/rad/counts (uint4 stores; in-graph hipMemsetAsync fill was pathological)
    int n16 = (int)((off_vox + 15) / 16);
    k_zero<<<(n16 + 255) / 256, 256, 0, stream>>>((uint4*)ws, n16);

    k_sum_coords<<<BB * NB_STAT, 256, 0, stream>>>(coords, sums);
    k_radius<<<BB * NB_STAT, 256, 0, stream>>>(coords, sums, rad_bits);

    int pts_blocks = (NPTS_TOT + 255) / 256;
    k_voxelize<<<pts_blocks, 256, 0, stream>>>(coords, sums, rad_bits, norm_out, voxidx, counts);

    k_accum<<<BB * FF * 2, 256, 0, stream>>>(features, voxidx, counts, grid);
}

// Round 9
// 364.254 us; speedup vs baseline: 1.0823x; 1.0823x over previous
//
#include <hip/hip_runtime.h>
#include <hip/hip_bf16.h>

#define BB 8
#define FF 64
#define NPTS 100000
#define RES 32
#define R3 (RES*RES*RES)
#define EPSV 1e-6f
#define SEGS (BB*R3)            // 262144 voxel cells total
#define NPTS_TOT (BB*NPTS)      // 800000 points

static constexpr size_t GRID_ELEMS = (size_t)BB * FF * R3;   // 16,777,216

// ---------------- Kernel Z: fast zero (sums/rad/counts) ----------------
__global__ void k_zero(uint4* __restrict__ p, int n16) {
    int i = blockIdx.x * 256 + threadIdx.x;
    if (i < n16) p[i] = make_uint4(0u, 0u, 0u, 0u);
}

// ---------------- Kernel A: per-batch coordinate sums ----------------
#define NB_STAT 64
__global__ void k_sum_coords(const float* __restrict__ coords, float* __restrict__ sums) {
    int b = blockIdx.x / NB_STAT;
    int chunk = blockIdx.x % NB_STAT;
    const float* cb = coords + (size_t)b * 3 * NPTS;
    float sx = 0.f, sy = 0.f, sz = 0.f;
    for (int i = chunk * blockDim.x + threadIdx.x; i < NPTS; i += NB_STAT * blockDim.x) {
        sx += cb[i];
        sy += cb[NPTS + i];
        sz += cb[2 * NPTS + i];
    }
    for (int off = 32; off; off >>= 1) {
        sx += __shfl_down(sx, off);
        sy += __shfl_down(sy, off);
        sz += __shfl_down(sz, off);
    }
    __shared__ float lsx[4], lsy[4], lsz[4];
    int lane = threadIdx.x & 63, wid = threadIdx.x >> 6;
    if (lane == 0) { lsx[wid] = sx; lsy[wid] = sy; lsz[wid] = sz; }
    __syncthreads();
    if (threadIdx.x == 0) {
        float tx = 0.f, ty = 0.f, tz = 0.f;
        for (int w = 0; w < 4; ++w) { tx += lsx[w]; ty += lsy[w]; tz += lsz[w]; }
        atomicAdd(&sums[b * 3 + 0], tx);
        atomicAdd(&sums[b * 3 + 1], ty);
        atomicAdd(&sums[b * 3 + 2], tz);
    }
}

// ---------------- Kernel B: per-batch max radius ----------------
__global__ void k_radius(const float* __restrict__ coords, const float* __restrict__ sums,
                         int* __restrict__ rad_bits) {
    int b = blockIdx.x / NB_STAT;
    int chunk = blockIdx.x % NB_STAT;
    const float* cb = coords + (size_t)b * 3 * NPTS;
    float mx = sums[b * 3 + 0] / (float)NPTS;
    float my = sums[b * 3 + 1] / (float)NPTS;
    float mz = sums[b * 3 + 2] / (float)NPTS;
    float mval = 0.f;
    for (int i = chunk * blockDim.x + threadIdx.x; i < NPTS; i += NB_STAT * blockDim.x) {
        float x = cb[i] - mx;
        float y = cb[NPTS + i] - my;
        float z = cb[2 * NPTS + i] - mz;
        float nrm = sqrtf(x * x + y * y + z * z);
        mval = fmaxf(mval, nrm);
    }
    for (int off = 32; off; off >>= 1) mval = fmaxf(mval, __shfl_down(mval, off));
    __shared__ float lm[4];
    int lane = threadIdx.x & 63, wid = threadIdx.x >> 6;
    if (lane == 0) lm[wid] = mval;
    __syncthreads();
    if (threadIdx.x == 0) {
        float t = fmaxf(fmaxf(lm[0], lm[1]), fmaxf(lm[2], lm[3]));
        atomicMax(&rad_bits[b], __float_as_int(t));  // norms >= 0: int order == float order
    }
}

// ---------------- Kernel C: per-point voxelize + norm_coords + counts ----------------
__global__ void k_voxelize(const float* __restrict__ coords, const float* __restrict__ sums,
                           const int* __restrict__ rad_bits, float* __restrict__ norm_out,
                           int* __restrict__ voxidx, int* __restrict__ counts) {
    int tid = blockIdx.x * blockDim.x + threadIdx.x;
    if (tid >= NPTS_TOT) return;
    int b = tid / NPTS, n = tid % NPTS;
    const float* cb = coords + (size_t)b * 3 * NPTS;
    float mx = sums[b * 3 + 0] / (float)NPTS;
    float my = sums[b * 3 + 1] / (float)NPTS;
    float mz = sums[b * 3 + 2] / (float)NPTS;
    float r = __int_as_float(rad_bits[b]);
    float d = 2.0f * r + EPSV;
    float x = (cb[n] - mx) / d + 0.5f;
    float y = (cb[NPTS + n] - my) / d + 0.5f;
    float z = (cb[2 * NPTS + n] - mz) / d + 0.5f;
    float nx = fminf(fmaxf(x * (float)RES, 0.0f), (float)(RES - 1));
    float ny = fminf(fmaxf(y * (float)RES, 0.0f), (float)(RES - 1));
    float nz = fminf(fmaxf(z * (float)RES, 0.0f), (float)(RES - 1));
    float* nb_ = norm_out + (size_t)b * 3 * NPTS;
    nb_[n] = nx;
    nb_[NPTS + n] = ny;
    nb_[2 * NPTS + n] = nz;
    int vx = (int)rintf(nx), vy = (int)rintf(ny), vz = (int)rintf(nz);
    int idx = (vx * RES + vy) * RES + vz;
    voxidx[tid] = idx;
    atomicAdd(&counts[b * R3 + idx], 1);
}

// ---------------- Kernel D: direct LDS-accumulate, one block per (b, f) ----------------
// Full 32^3 f32 slab (128 KB LDS) per block; 1024 threads (16 waves, 1 block/CU).
// Streams features[b][f][:] once (float4) + voxidx[b][:] (L2-resident: all 64 features
// of batch b land on XCD b), LDS atomicAdd, then fused count-divide coalesced writeout.
__global__ __launch_bounds__(1024) void k_accum(const float* __restrict__ features,
                                                const int* __restrict__ voxidx,
                                                const int* __restrict__ counts,
                                                float* __restrict__ grid) {
    __shared__ float vox[R3];          // 128 KB
    // XCD mapping: hardware round-robins blocks over XCDs (xcd = bid % 8).
    // bf = (bid&7)*64 + (bid>>3) gives b = bid&7 == xcd -> each XCD owns one batch,
    // so the shared voxidx[b] row (400 KB) stays L2-resident on that XCD.
    int bid = blockIdx.x;              // [0, 512)
    int bf = ((bid & 7) << 6) | (bid >> 3);
    int b = bf >> 6;

    const float4* frow = (const float4*)(features + (size_t)bf * NPTS);
    const int4* vrow = (const int4*)(voxidx + (size_t)b * NPTS);

    for (int i = threadIdx.x; i < R3; i += 1024) vox[i] = 0.f;
    __syncthreads();

    const int NV = NPTS / 4;           // 25000
#pragma unroll 2
    for (int i = threadIdx.x; i < NV; i += 1024) {
        float4 f4 = frow[i];
        int4 v4 = vrow[i];
        atomicAdd(&vox[v4.x], f4.x);
        atomicAdd(&vox[v4.y], f4.y);
        atomicAdd(&vox[v4.z], f4.z);
        atomicAdd(&vox[v4.w], f4.w);
    }
    __syncthreads();

    const int* crow = counts + b * R3;
    float* grow = grid + (size_t)bf * R3;
    for (int i = threadIdx.x; i < R3; i += 1024) {
        int cnt = crow[i];
        grow[i] = (cnt > 0) ? vox[i] / (float)cnt : 0.f;   // empty voxels stay 0
    }
}

extern "C" void kernel_launch(void* const* d_in, const int* in_sizes, int n_in,
                              void* d_out, int out_size, void* d_ws, size_t ws_size,
                              hipStream_t stream) {
    const float* features = (const float*)d_in[0];
    const float* coords = (const float*)d_in[1];
    float* out = (float*)d_out;
    float* grid = out;                      // [B,F,R,R,R]
    float* norm_out = out + GRID_ELEMS;     // [B,3,N]

    char* ws = (char*)d_ws;
    size_t off_sums   = 0;                               // 24 floats
    size_t off_rad    = 128;                             // 8 ints
    size_t off_counts = 256;                             // SEGS ints (1 MB)
    size_t off_vox    = off_counts + (size_t)SEGS * 4;   // NPTS_TOT ints (3.2 MB)

    float* sums   = (float*)(ws + off_sums);
    int* rad_bits = (int*)(ws + off_rad);
    int* counts   = (int*)(ws + off_counts);
    int* voxidx   = (int*)(ws + off_vox);

    // zero sums/rad/counts (uint4 stores; in-graph hipMemsetAsync fill was pathological)
    int n16 = (int)((off_vox + 15) / 16);
    k_zero<<<(n16 + 255) / 256, 256, 0, stream>>>((uint4*)ws, n16);

    k_sum_coords<<<BB * NB_STAT, 256, 0, stream>>>(coords, sums);
    k_radius<<<BB * NB_STAT, 256, 0, stream>>>(coords, sums, rad_bits);

    int pts_blocks = (NPTS_TOT + 255) / 256;
    k_voxelize<<<pts_blocks, 256, 0, stream>>>(coords, sums, rad_bits, norm_out, voxidx, counts);

    k_accum<<<BB * FF, 1024, 0, stream>>>(features, voxidx, counts, grid);
}